// Round 2
// 416.124 us; speedup vs baseline: 1.0064x; 1.0064x over previous
//
#include <hip/hip_runtime.h>
#include <hip/hip_bf16.h>

// HNNLayer fused kernel. ALL tensors are FP32 (reference is jnp.float32; the
// bench threshold is merely bf16-floored to permit internal bf16 compute).
//   x[N=131072][512] f32, W1[50][512] f32, b1[50] f32, W3[128][50] f32,
//   b3[128] f32, out[N][128] f32.
// R2: 32 rows/wave (LDS 60,416 -> 39,688 B -> 4 blocks/CU by LDS) but KEEP
// __launch_bounds__(256,2): R1's (256,4) imposed a 128-reg cap on the unified
// VGPR/AGPR file and failed correctness (absmax 0.039) -- suspected
// cap-induced AGPR spill miscompile. No register cap here; the slimmer
// acc[2][4] kernel should land ~100-124 regs naturally (<=128 => 4 waves/SIMD).
// block = 4 waves -> 128 rows/block, grid = N/128 = 1024 blocks.
// GEMM1/GEMM2 run on bf16 MFMA (inputs converted RNE inline); all norms and
// scalar chains in fp32.

#define DIN  512
#define HH   50
#define DOUT 128
#define MAXN 0.996f      // (1 - 4e-3)/sqrt(c), c=1
#define MINN 1e-15f

typedef __bf16 bf16x8 __attribute__((ext_vector_type(8)));
typedef float  f32x4  __attribute__((ext_vector_type(4)));

__device__ __forceinline__ float artanh_c(float z) {
    z = fminf(z, 0.9999999f);          // jax clamp to open (-1,1); z >= 0 here
    return atanhf(z);
}
__device__ __forceinline__ unsigned short f2bf(float f) {
    union { float f; unsigned int i; } v;
    v.f = f;
    unsigned int i = v.i;
    i += 0x7fffu + ((i >> 16) & 1u);   // round-to-nearest-even
    return (unsigned short)(i >> 16);
}
__device__ __forceinline__ bf16x8 pack8(float4 a, float4 b) {
    union { bf16x8 v; unsigned short u[8]; } r;
    r.u[0] = f2bf(a.x); r.u[1] = f2bf(a.y); r.u[2] = f2bf(a.z); r.u[3] = f2bf(a.w);
    r.u[4] = f2bf(b.x); r.u[5] = f2bf(b.y); r.u[6] = f2bf(b.z); r.u[7] = f2bf(b.w);
    return r.v;
}

__global__ __launch_bounds__(256, 2)
void hnn_fused(const float* __restrict__ xg,
               const float* __restrict__ w1,
               const float* __restrict__ b1g,
               const float* __restrict__ w3,
               const float* __restrict__ b3g,
               float* __restrict__ outg)
{
    // LDS: 18432 + 18432 + 2048 + 256 + 512 + 8 = 39688 B -> 4 blocks/CU.
    __shared__ __align__(16) unsigned short W3p[DOUT][72];   // W3 (bf16) zero-padded to K=64 (stride 72)
    __shared__ __align__(16) unsigned short A2[4][32][72];   // per-wave GEMM2 A operand (t, bf16)
    __shared__ float scal[4][32][4];                         // per-wave per-row scalar scratch
    __shared__ float hb1s[64];                               // proj(expmap0(b1)), zero-padded
    __shared__ float hb3s[DOUT];                             // proj(expmap0(b3))
    __shared__ float hbc[2];                                 // ||hb1||^2, ||hb3||^2

    const int tid  = threadIdx.x;
    const int w    = tid >> 6;     // wave id in block
    const int lane = tid & 63;
    const int c    = lane & 15;    // MFMA "column lane" index
    const int q    = lane >> 4;    // MFMA quad

    // ---------------- one-time block staging ----------------
    for (int i = tid; i < DOUT * 72; i += 256) {
        int o = i / 72, k = i - o * 72;
        W3p[o][k] = (k < HH) ? f2bf(w3[o * HH + k]) : (unsigned short)0;
    }
    if (w == 0) {  // hyp_b1 = proj(expmap0(b1))
        float b = (lane < HH) ? b1g[lane] : 0.f;
        float ss = b * b;
        #pragma unroll
        for (int m = 1; m < 64; m <<= 1) ss += __shfl_xor(ss, m);
        float bn = fmaxf(sqrtf(fmaxf(ss, 0.f)), MINN);
        float tb = tanhf(bn);
        float f  = tb / bn;                 // expmap0 scale
        float nn = fmaxf(tb, MINN);         // ||expmap0(b)||
        if (nn > MAXN) f *= MAXN / nn;      // proj
        hb1s[lane] = (lane < HH) ? f * b : 0.f;
        if (lane == 0) { float h = fminf(nn, MAXN); hbc[0] = h * h; }
    } else if (w == 1) {  // hyp_b3
        float ba = b3g[lane];
        float bb = b3g[lane + 64];
        float ss = ba * ba + bb * bb;
        #pragma unroll
        for (int m = 1; m < 64; m <<= 1) ss += __shfl_xor(ss, m);
        float bn = fmaxf(sqrtf(fmaxf(ss, 0.f)), MINN);
        float tb = tanhf(bn);
        float f  = tb / bn;
        float nn = fmaxf(tb, MINN);
        if (nn > MAXN) f *= MAXN / nn;
        hb3s[lane]      = f * ba;
        hb3s[lane + 64] = f * bb;
        if (lane == 0) { float h = fminf(nn, MAXN); hbc[1] = h * h; }
    }
    __syncthreads();   // barrier 0: staging -> everything

    const long base = ((long)blockIdx.x * 4 + w) * 32;
    const float* xb = xg + base * DIN;

    float hb1v[4];
    #pragma unroll
    for (int t = 0; t < 4; t++) hb1v[t] = hb1s[c + 16 * t];
    const float hb1sq = hbc[0];
    const float hb3sq = hbc[1];

    // ---------------- GEMM1: g = x @ W1^T  (fp32 row sumsq alongside the convert) ----------------
    f32x4 acc[2][4];   // [row_tile][col_tile]; C layout: col=lane&15, row=q*4+reg
    float sq[2] = {0.f, 0.f};
    #pragma unroll
    for (int rt = 0; rt < 2; rt++)
        #pragma unroll
        for (int ct = 0; ct < 4; ct++) acc[rt][ct] = (f32x4){0.f, 0.f, 0.f, 0.f};

    for (int k0 = 0; k0 < DIN; k0 += 32) {
        bf16x8 af[2], bfr[4];
        #pragma unroll
        for (int rt = 0; rt < 2; rt++) {  // A[m=lane&15][k=q*8+j]
            const float* p = xb + (long)(16 * rt + c) * DIN + k0 + q * 8;
            float4 a = *(const float4*)p;
            float4 b = *(const float4*)(p + 4);
            af[rt] = pack8(a, b);
            sq[rt] += a.x * a.x + a.y * a.y + a.z * a.z + a.w * a.w
                    + b.x * b.x + b.y * b.y + b.z * b.z + b.w * b.w;
        }
        #pragma unroll
        for (int ct = 0; ct < 4; ct++) {  // B[n=lane&15][k]; clamp pad cols to row 49 (masked later)
            int wr = c + 16 * ct; if (wr > HH - 1) wr = HH - 1;
            const float* p = w1 + (long)wr * DIN + k0 + q * 8;
            float4 a = *(const float4*)p;
            float4 b = *(const float4*)(p + 4);
            bfr[ct] = pack8(a, b);
        }
        #pragma unroll
        for (int rt = 0; rt < 2; rt++)
            #pragma unroll
            for (int ct = 0; ct < 4; ct++)
                acc[rt][ct] = __builtin_amdgcn_mfma_f32_16x16x32_bf16(af[rt], bfr[ct], acc[rt][ct], 0, 0, 0);
    }

    // nsq per row (fp32, exact stream): reduce sq over the 4 q-groups
    #pragma unroll
    for (int rt = 0; rt < 2; rt++) {
        float s = sq[rt];
        s += __shfl_xor(s, 16);
        s += __shfl_xor(s, 32);
        if (q == 0) scal[w][16 * rt + c][0] = s;
    }

    // gsq = sum_j g^2, gdot = sum_j g*hb1  (cols >= 50 masked; reduce over 16 col-lanes)
    #pragma unroll
    for (int rt = 0; rt < 2; rt++) {
        #pragma unroll
        for (int reg = 0; reg < 4; reg++) {
            float gs = 0.f, gd = 0.f;
            #pragma unroll
            for (int ct = 0; ct < 4; ct++) {
                float g = acc[rt][ct][reg];
                float gm = (ct < 3 || c < 2) ? g : 0.f;   // col = c+16*ct < 50
                gs += gm * gm;
                gd += gm * hb1v[ct];
            }
            #pragma unroll
            for (int m = 1; m < 16; m <<= 1) { gs += __shfl_xor(gs, m); gd += __shfl_xor(gd, m); }
            if (c == 0) {
                scal[w][16 * rt + 4 * q + reg][1] = gs;
                scal[w][16 * rt + 4 * q + reg][2] = gd;
            }
        }
    }
    __syncthreads();   // barrier 1: nsq/gsq/gdot -> chain 1

    // ---------------- per-row scalar chain 1 (lane = row, rows 0..31): hyp_linear1 + logmap0 ----------------
    if (lane < 32) {
        float nsq = scal[w][lane][0];
        float gsq = scal[w][lane][1];
        float gdo = scal[w][lane][2];
        float n0  = fmaxf(sqrtf(fmaxf(nsq, 0.f)), MINN);
        float tn0 = tanhf(n0);
        float s   = tn0 / n0;                 // expmap0 scale: h = s*x
        float xn  = fmaxf(tn0, MINN);         // ||h||
        float gn  = sqrtf(fmaxf(gsq, 0.f));
        float mxn = fmaxf(s * gn, MINN);      // ||mx|| = ||s*g||
        float F   = tanhf(mxn / xn * artanh_c(xn));
        float al  = F * s / mxn;              // res = al * g
        if (F > MAXN) al *= MAXN / F;         // proj(res), ||res|| = F
        float rn  = fminf(F, MAXN);
        float xy  = al * gdo;                 // <res, hb1>
        float x2  = rn * rn;
        float den = fmaxf(1.f + 2.f * xy + x2 * hb1sq, MINN);
        float be  = (1.f + 2.f * xy + hb1sq) * al / den;   // madd = be*g + ga*hb1
        float ga  = (1.f - x2) / den;
        float mnsq = be * be * gsq + 2.f * be * ga * gdo + ga * ga * hb1sq;
        float mn  = fmaxf(sqrtf(fmaxf(mnsq, 0.f)), MINN);
        if (mn > MAXN) { float pf = MAXN / mn; be *= pf; ga *= pf; mn = MAXN; }  // proj
        float lt  = artanh_c(mn) / mn;        // logmap0 scale
        scal[w][lane][0] = lt * be;
        scal[w][lane][1] = lt * ga;
    }
    __syncthreads();   // barrier 2: chain-1 scalars -> elementwise

    // ---------------- elementwise: xt = lbx*g + lby*hb1; leaky; unsq; A2 = bf16(t) ----------------
    #pragma unroll
    for (int rt = 0; rt < 2; rt++) {
        #pragma unroll
        for (int reg = 0; reg < 4; reg++) {
            const int row = 16 * rt + 4 * q + reg;
            float lbx = scal[w][row][0];
            float lby = scal[w][row][1];
            float us = 0.f;
            #pragma unroll
            for (int ct = 0; ct < 4; ct++) {
                float g = acc[rt][ct][reg];
                float t = lbx * g + lby * hb1v[ct];
                t = (t > 0.f) ? t : 0.01f * t;            // LeakyReLU(0.01)
                if (ct == 3 && c >= 2) t = 0.f;           // zero pad cols >= 50
                us += t * t;
                A2[w][row][c + 16 * ct] = f2bf(t);
            }
            #pragma unroll
            for (int m = 1; m < 16; m <<= 1) us += __shfl_xor(us, m);
            if (c == 0) scal[w][row][3] = us;
        }
    }
    __syncthreads();   // barrier 3: A2 + unsq -> chain 2 / GEMM2

    // ---------------- chain 2: expmap0 + proj -> per-row es (factored out of GEMM2), xn2 ----------------
    float es = 0.f, xn2 = 1.f;
    if (lane < 32) {
        float us  = scal[w][lane][3];
        float un  = fmaxf(sqrtf(fmaxf(us, 0.f)), MINN);
        float tun = tanhf(un);
        es = tun / un;                         // qv = es * t
        float qn = tun;
        if (tun > MAXN) { es *= MAXN / tun; qn = MAXN; }   // proj
        xn2 = fmaxf(qn, MINN);
    }

    // ---------------- GEMM2 pass 1: G2 = t @ W3^T; reduce G2sq, G2dot ----------------
    float hb3v[8];
    #pragma unroll
    for (int t = 0; t < 8; t++) hb3v[t] = hb3s[c + 16 * t];

    bf16x8 afr[2][2];
    #pragma unroll
    for (int rt = 0; rt < 2; rt++) {
        afr[rt][0] = *(const bf16x8*)&A2[w][c + 16 * rt][q * 8];
        afr[rt][1] = *(const bf16x8*)&A2[w][c + 16 * rt][32 + q * 8];
    }

    float g2s[2][4], g2d[2][4];
    #pragma unroll
    for (int rt = 0; rt < 2; rt++)
        #pragma unroll
        for (int reg = 0; reg < 4; reg++) { g2s[rt][reg] = 0.f; g2d[rt][reg] = 0.f; }

    #pragma unroll
    for (int ct = 0; ct < 8; ct++) {
        bf16x8 b0  = *(const bf16x8*)&W3p[c + 16 * ct][q * 8];
        bf16x8 b1f = *(const bf16x8*)&W3p[c + 16 * ct][32 + q * 8];
        #pragma unroll
        for (int rt = 0; rt < 2; rt++) {
            f32x4 a = (f32x4){0.f, 0.f, 0.f, 0.f};
            a = __builtin_amdgcn_mfma_f32_16x16x32_bf16(afr[rt][0], b0,  a, 0, 0, 0);
            a = __builtin_amdgcn_mfma_f32_16x16x32_bf16(afr[rt][1], b1f, a, 0, 0, 0);
            #pragma unroll
            for (int reg = 0; reg < 4; reg++) {
                float v = a[reg];
                g2s[rt][reg] += v * v;
                g2d[rt][reg] += v * hb3v[ct];
            }
        }
    }
    #pragma unroll
    for (int rt = 0; rt < 2; rt++) {
        #pragma unroll
        for (int reg = 0; reg < 4; reg++) {
            float s1 = g2s[rt][reg], s2 = g2d[rt][reg];
            #pragma unroll
            for (int m = 1; m < 16; m <<= 1) { s1 += __shfl_xor(s1, m); s2 += __shfl_xor(s2, m); }
            if (c == 0) {
                scal[w][16 * rt + 4 * q + reg][0] = s1;
                scal[w][16 * rt + 4 * q + reg][1] = s2;
            }
        }
    }
    __syncthreads();   // barrier 4: G2sq/G2dot -> chain D

    // ---------------- per-row scalar chain D: hyp_linear2 scalars ----------------
    if (lane < 32) {
        float G2sq = scal[w][lane][0];
        float G2do = scal[w][lane][1];
        float gn2  = sqrtf(fmaxf(G2sq, 0.f));
        float mxn2 = fmaxf(es * gn2, MINN);               // ||mx2|| = ||es*G2||
        float F2   = tanhf(mxn2 / xn2 * artanh_c(xn2));
        float al2  = F2 * es / mxn2;                      // res2 = al2 * G2
        if (F2 > MAXN) al2 *= MAXN / F2;                  // proj
        float rn2  = fminf(F2, MAXN);
        float xy2  = al2 * G2do;
        float x22  = rn2 * rn2;
        float den2 = fmaxf(1.f + 2.f * xy2 + x22 * hb3sq, MINN);
        float be2  = (1.f + 2.f * xy2 + hb3sq) * al2 / den2;
        float ga2  = (1.f - x22) / den2;
        float fnsq = be2 * be2 * G2sq + 2.f * be2 * ga2 * G2do + ga2 * ga2 * hb3sq;
        float fn   = fmaxf(sqrtf(fmaxf(fnsq, 0.f)), MINN);
        if (fn > MAXN) { float pf = MAXN / fn; be2 *= pf; ga2 *= pf; }  // final proj
        scal[w][lane][2] = be2;
        scal[w][lane][3] = ga2;
    }
    __syncthreads();   // barrier 5: be2/ga2 -> epilogue

    // ---------------- GEMM2 pass 2 (recompute) + epilogue + fp32 store ----------------
    float bx2[2][4], by2[2][4];
    #pragma unroll
    for (int rt = 0; rt < 2; rt++)
        #pragma unroll
        for (int reg = 0; reg < 4; reg++) {
            bx2[rt][reg] = scal[w][16 * rt + 4 * q + reg][2];
            by2[rt][reg] = scal[w][16 * rt + 4 * q + reg][3];
        }

    float* ob = outg + base * DOUT;
    #pragma unroll
    for (int ct = 0; ct < 8; ct++) {
        bf16x8 b0  = *(const bf16x8*)&W3p[c + 16 * ct][q * 8];
        bf16x8 b1f = *(const bf16x8*)&W3p[c + 16 * ct][32 + q * 8];
        #pragma unroll
        for (int rt = 0; rt < 2; rt++) {
            f32x4 a = (f32x4){0.f, 0.f, 0.f, 0.f};
            a = __builtin_amdgcn_mfma_f32_16x16x32_bf16(afr[rt][0], b0,  a, 0, 0, 0);
            a = __builtin_amdgcn_mfma_f32_16x16x32_bf16(afr[rt][1], b1f, a, 0, 0, 0);
            #pragma unroll
            for (int reg = 0; reg < 4; reg++) {
                float v = bx2[rt][reg] * a[reg] + by2[rt][reg] * hb3v[ct];
                ob[(long)(16 * rt + 4 * q + reg) * DOUT + c + 16 * ct] = v;
            }
        }
    }
}

extern "C" void kernel_launch(void* const* d_in, const int* in_sizes, int n_in,
                              void* d_out, int out_size, void* d_ws, size_t ws_size,
                              hipStream_t stream) {
    const float* x  = (const float*)d_in[0];
    const float* w1 = (const float*)d_in[1];
    const float* b1 = (const float*)d_in[2];
    const float* w3 = (const float*)d_in[3];
    const float* b3 = (const float*)d_in[4];
    float* out = (float*)d_out;

    int N = in_sizes[0] / DIN;          // 131072
    int blocks = N / 128;               // 4 waves * 32 rows per block
    hnn_fused<<<dim3(blocks), dim3(256), 0, stream>>>(x, w1, b1, w3, b3, out);
}